// Round 4
// baseline (1894.086 us; speedup 1.0000x reference)
//
#include <hip/hip_runtime.h>

#define MTOT 25088
#define DMODEL 768
#define NH 12
#define WIN 49
#define NLAYER 2

typedef short bf16x8 __attribute__((ext_vector_type(8)));
typedef float f32x4 __attribute__((ext_vector_type(4)));
typedef unsigned short u16x4 __attribute__((ext_vector_type(4)));

__device__ __forceinline__ float bf2f(short s) {
    return __uint_as_float(((unsigned)(unsigned short)s) << 16);
}
__device__ __forceinline__ short f2b(float f) {
    unsigned x = __float_as_uint(f);
    unsigned r = x + 0x7FFFu + ((x >> 16) & 1u);
    return (short)(r >> 16);
}

// ---------------- fp32 -> bf16 weight conversion ----------------
__global__ __launch_bounds__(256) void cvt_f32_to_bf16(const float* __restrict__ in,
                                                       short* __restrict__ out, int n8) {
    int i = blockIdx.x * 256 + threadIdx.x;
    if (i >= n8) return;
    const float4* p = (const float4*)in + (size_t)i * 2;
    float4 a = p[0], b = p[1];
    bf16x8 o;
    o[0] = f2b(a.x); o[1] = f2b(a.y); o[2] = f2b(a.z); o[3] = f2b(a.w);
    o[4] = f2b(b.x); o[5] = f2b(b.y); o[6] = f2b(b.z); o[7] = f2b(b.w);
    *((bf16x8*)out + i) = o;
}

// ---------------- LayerNorm (fp32 in, bf16 out), 1 wave per row ----------------
__global__ __launch_bounds__(256) void ln_to_bf16(const float* __restrict__ h,
                                                  const float* __restrict__ w,
                                                  const float* __restrict__ b,
                                                  short* __restrict__ y) {
    int wave = threadIdx.x >> 6, lane = threadIdx.x & 63;
    int row = blockIdx.x * 4 + wave;
    const float4* hp = (const float4*)(h + (size_t)row * DMODEL);
    float4 v[3];
    float s = 0.f, s2 = 0.f;
#pragma unroll
    for (int c = 0; c < 3; c++) {
        v[c] = hp[lane + 64 * c];
        s += v[c].x + v[c].y + v[c].z + v[c].w;
        s2 += v[c].x * v[c].x + v[c].y * v[c].y + v[c].z * v[c].z + v[c].w * v[c].w;
    }
#pragma unroll
    for (int off = 32; off > 0; off >>= 1) {
        s += __shfl_xor(s, off);
        s2 += __shfl_xor(s2, off);
    }
    float mean = s * (1.f / DMODEL);
    float var = s2 * (1.f / DMODEL) - mean * mean;
    float rstd = rsqrtf(var + 1e-5f);
#pragma unroll
    for (int c = 0; c < 3; c++) {
        float4 wv = ((const float4*)w)[lane + 64 * c];
        float4 bv = ((const float4*)b)[lane + 64 * c];
        u16x4 o;
        o[0] = (unsigned short)f2b((v[c].x - mean) * rstd * wv.x + bv.x);
        o[1] = (unsigned short)f2b((v[c].y - mean) * rstd * wv.y + bv.y);
        o[2] = (unsigned short)f2b((v[c].z - mean) * rstd * wv.z + bv.z);
        o[3] = (unsigned short)f2b((v[c].w - mean) * rstd * wv.w + bv.w);
        *(u16x4*)(y + (size_t)row * DMODEL + (size_t)(lane + 64 * c) * 4) = o;
    }
}

// ---------------- unified GEMM: C[M,N] = A[M,K](bf16) @ B[N,K](bf16)^T + bias ----------------
// BM=256, BN=128, BK=32, 256 threads (4 waves 2x2), per-wave 128x64, 2 blocks/CU.
// EPI 0: bf16 = v+bias ; EPI 1: fp32 C += v+bias ; EPI 2: bf16 = gelu(v+bias)
#define BAR() asm volatile("s_barrier" ::: "memory")
#define LGKM0() do { asm volatile("s_waitcnt lgkmcnt(0)" ::: "memory"); __builtin_amdgcn_sched_barrier(0); } while (0)

template <int EPI>
__global__ __launch_bounds__(256, 2)
void gemm_u(const short* __restrict__ A, const short* __restrict__ B,
            const float* __restrict__ bias, void* __restrict__ C,
            int N, int K, int gx) {
    // LDS: A [2][256][32]bf16 = 2*16KB at 0 ; B [2][128][32] = 2*8KB at 32768
    __shared__ char lds[49152];
    const int tid = threadIdx.x;
    const int wave = tid >> 6, lane = tid & 63;
    const int wr = wave >> 1, wc = wave & 1;
    const int fr = lane & 15, rq = lane >> 4;

    // bijective XCD swizzle (m204); consecutive lid -> same bm (A-panel L2 reuse)
    int nwg = gridDim.x, orig = blockIdx.x;
    int q8 = nwg >> 3, r8 = nwg & 7;
    int xcd = orig & 7, lid = orig >> 3;
    int wg = (xcd < r8 ? xcd * (q8 + 1) : r8 * (q8 + 1) + (xcd - r8) * q8) + lid;
    const int bn = wg % gx, bm = wg / gx;
    const int row0 = bm * 256, col0 = bn * 128;
    const int nt = K >> 5;

    const short* Ag = A + (size_t)row0 * K;
    const short* Bg = B + (size_t)col0 * K;
    // per-lane source row-in-segment and pre-swizzled column (element units)
    const int lrow = lane >> 2;                       // 0..15
    const int lcol = ((lane & 3) ^ (lrow & 3)) * 8;   // inverse of read-side XOR

#define STAGE(T) do { int ts_ = ((T) < nt ? (T) : (nt - 1));                                       \
    _Pragma("unroll") for (int j = 0; j < 4; j++) {                                                \
      int seg_ = wave * 4 + j;                                                                     \
      __builtin_amdgcn_global_load_lds(                                                            \
        (const __attribute__((address_space(1))) void*)(Ag + (size_t)(seg_ * 16 + lrow) * K + ts_ * 32 + lcol), \
        (__attribute__((address_space(3))) void*)(lds + (((T) & 1) * 16384 + seg_ * 1024)),        \
        16, 0, 0); }                                                                               \
    _Pragma("unroll") for (int j = 0; j < 2; j++) {                                                \
      int seg_ = wave * 2 + j;                                                                     \
      __builtin_amdgcn_global_load_lds(                                                            \
        (const __attribute__((address_space(1))) void*)(Bg + (size_t)(seg_ * 16 + lrow) * K + ts_ * 32 + lcol), \
        (__attribute__((address_space(3))) void*)(lds + (32768 + ((T) & 1) * 8192 + seg_ * 1024)), \
        16, 0, 0); } } while (0)

    // read-side: row-major [.][32] bf16 rows (64B), XOR bankquad with (row&3)
#define LDA(m, BUF) (*(const bf16x8*)(lds + ((BUF) * 16384 +                                        \
    (wr * 128 + (m) * 16 + fr) * 64 + ((rq * 16) ^ ((fr & 3) << 4)))))
#define LDB(n, BUF) (*(const bf16x8*)(lds + (32768 + (BUF) * 8192 +                                 \
    (wc * 64 + (n) * 16 + fr) * 64 + ((rq * 16) ^ ((fr & 3) << 4)))))

    f32x4 acc[8][4] = {};

    STAGE(0);
    STAGE(1);
    asm volatile("s_waitcnt vmcnt(6)" ::: "memory");
    BAR();

    for (int t = 0; t < nt; t++) {
        const int buf = t & 1;
        bf16x8 a[8], b[4];
#pragma unroll
        for (int m = 0; m < 8; m++) a[m] = LDA(m, buf);
#pragma unroll
        for (int n = 0; n < 4; n++) b[n] = LDB(n, buf);
        LGKM0();            // own reads landed in regs
        BAR();              // all waves done reading buf
        STAGE(t + 2);       // overwrite buf with tile t+2 (issue early)
        __builtin_amdgcn_s_setprio(1);
#pragma unroll
        for (int m = 0; m < 8; m++) {
#pragma unroll
            for (int n = 0; n < 4; n++)
                acc[m][n] = __builtin_amdgcn_mfma_f32_16x16x32_bf16(a[m], b[n], acc[m][n], 0, 0, 0);
        }
        __builtin_amdgcn_s_setprio(0);
        asm volatile("s_waitcnt vmcnt(6)" ::: "memory");  // t+1 fully arrived
        BAR();
    }
    asm volatile("s_waitcnt vmcnt(0)" ::: "memory");  // drain before LDS dealloc

    // epilogue: C/D layout col=lane&15, row=(lane>>4)*4+reg
#pragma unroll
    for (int m = 0; m < 8; m++) {
#pragma unroll
        for (int n = 0; n < 4; n++) {
            int col = col0 + wc * 64 + n * 16 + fr;
            float bv = bias[col];
#pragma unroll
            for (int rg = 0; rg < 4; rg++) {
                int row = row0 + wr * 128 + m * 16 + rq * 4 + rg;
                size_t idx = (size_t)row * N + col;
                float v = acc[m][n][rg] + bv;
                if constexpr (EPI == 0) {
                    ((short*)C)[idx] = f2b(v);
                } else if constexpr (EPI == 1) {
                    float* O = (float*)C;
                    O[idx] = O[idx] + v;
                } else {
                    float g = 0.5f * v * (1.0f + erff(v * 0.70710678118654752f));
                    ((short*)C)[idx] = f2b(g);
                }
            }
        }
    }
#undef STAGE
#undef LDA
#undef LDB
}

// ---------------- windowed attention: 1 wave per (window, head) ----------------
__global__ __launch_bounds__(64) void attn_win(const short* __restrict__ qkv,
                                               short* __restrict__ out) {
    const int win = blockIdx.x / NH;
    const int head = blockIdx.x % NH;
    __shared__ __align__(16) short Ks[WIN * 64];
    __shared__ __align__(16) short Vs[WIN * 64];
    __shared__ float Ps[64 * WIN];
    const int lane = threadIdx.x;
    const size_t rb = (size_t)win * WIN;
    const int qoff = head * 64;

    for (int i = lane; i < WIN * 8; i += 64) {
        int r = i >> 3, c = (i & 7) * 8;
        const short* kg = qkv + (rb + r) * 2304 + DMODEL + qoff + c;
        *(bf16x8*)(Ks + r * 64 + c) = *(const bf16x8*)kg;
        *(bf16x8*)(Vs + r * 64 + c) = *(const bf16x8*)(kg + DMODEL);
    }
    __syncthreads();
    if (lane < WIN) {
        float q[64];
        const short* qg = qkv + (rb + lane) * 2304 + qoff;
#pragma unroll
        for (int c = 0; c < 8; c++) {
            bf16x8 t = *(const bf16x8*)(qg + c * 8);
#pragma unroll
            for (int d = 0; d < 8; d++) q[c * 8 + d] = bf2f(t[d]);
        }
        float m = -1e30f;
        for (int j = 0; j < WIN; j++) {
            float a = 0.f;
#pragma unroll
            for (int c = 0; c < 8; c++) {
                bf16x8 kv = *(const bf16x8*)(Ks + j * 64 + c * 8);
#pragma unroll
                for (int d = 0; d < 8; d++) a += q[c * 8 + d] * bf2f(kv[d]);
            }
            a *= 0.125f;
            Ps[lane * WIN + j] = a;
            m = fmaxf(m, a);
        }
        float sum = 0.f;
        for (int j = 0; j < WIN; j++) {
            float p = __expf(Ps[lane * WIN + j] - m);
            Ps[lane * WIN + j] = p;
            sum += p;
        }
        float rinv = 1.f / sum;
        short* og = out + (rb + lane) * DMODEL + qoff;
        for (int c = 0; c < 8; c++) {
            float o[8] = {0.f, 0.f, 0.f, 0.f, 0.f, 0.f, 0.f, 0.f};
            for (int j = 0; j < WIN; j++) {
                float p = Ps[lane * WIN + j];
                bf16x8 vv = *(const bf16x8*)(Vs + j * 64 + c * 8);
#pragma unroll
                for (int d = 0; d < 8; d++) o[d] += p * bf2f(vv[d]);
            }
            bf16x8 ov;
#pragma unroll
            for (int d = 0; d < 8; d++) ov[d] = f2b(o[d] * rinv);
            *(bf16x8*)(og + c * 8) = ov;
        }
    }
}

extern "C" void kernel_launch(void* const* d_in, const int* in_sizes, int n_in,
                              void* d_out, int out_size, void* d_ws, size_t ws_size,
                              hipStream_t stream) {
    const float* x    = (const float*)d_in[0];
    const float* Wqkv = (const float*)d_in[1];
    const float* bqkv = (const float*)d_in[2];
    const float* Wo   = (const float*)d_in[3];
    const float* bo   = (const float*)d_in[4];
    const float* ln1w = (const float*)d_in[5];
    const float* ln1b = (const float*)d_in[6];
    const float* W1   = (const float*)d_in[7];
    const float* b1   = (const float*)d_in[8];
    const float* W2   = (const float*)d_in[9];
    const float* b2   = (const float*)d_in[10];
    const float* ln2w = (const float*)d_in[11];
    const float* ln2b = (const float*)d_in[12];

    const int M = MTOT;
    char* ws = (char*)d_ws;
    short* ybf   = (short*)(ws);
    short* bigbf = (short*)(ws + 38535168);
    short* wqkvb = (short*)(ws + 38535168 + 154140672);
    short* wob   = wqkvb + (size_t)NLAYER * 2304 * 768;
    short* w1b   = wob + (size_t)NLAYER * 768 * 768;
    short* w2b   = w1b + (size_t)NLAYER * 3072 * 768;

    hipMemcpyAsync(d_out, (const void*)x, (size_t)M * DMODEL * sizeof(float),
                   hipMemcpyDeviceToDevice, stream);

    {
        size_t n;
        n = (size_t)NLAYER * 2304 * 768;
        cvt_f32_to_bf16<<<((int)(n / 8) + 255) / 256, 256, 0, stream>>>(Wqkv, wqkvb, (int)(n / 8));
        n = (size_t)NLAYER * 768 * 768;
        cvt_f32_to_bf16<<<((int)(n / 8) + 255) / 256, 256, 0, stream>>>(Wo, wob, (int)(n / 8));
        n = (size_t)NLAYER * 3072 * 768;
        cvt_f32_to_bf16<<<((int)(n / 8) + 255) / 256, 256, 0, stream>>>(W1, w1b, (int)(n / 8));
        n = (size_t)NLAYER * 768 * 3072;
        cvt_f32_to_bf16<<<((int)(n / 8) + 255) / 256, 256, 0, stream>>>(W2, w2b, (int)(n / 8));
    }

    float* h = (float*)d_out;
    for (int l = 0; l < NLAYER; l++) {
        // y = LN1(h)
        ln_to_bf16<<<M / 4, 256, 0, stream>>>(h, ln1w + l * DMODEL, ln1b + l * DMODEL, ybf);
        // qkv = y @ Wqkv^T + bqkv : N=2304, K=768 -> grid 18*98
        gemm_u<0><<<dim3(18 * 98), 256, 0, stream>>>(
            ybf, wqkvb + (size_t)l * 2304 * 768, bqkv + (size_t)l * 2304, bigbf, 2304, 768, 18);
        // windowed attention (writes into ybf)
        attn_win<<<(M / WIN) * NH, 64, 0, stream>>>(bigbf, ybf);
        // h += attn @ Wo^T + bo : N=768, K=768 -> grid 6*98
        gemm_u<1><<<dim3(6 * 98), 256, 0, stream>>>(
            ybf, wob + (size_t)l * 768 * 768, bo + (size_t)l * 768, h, 768, 768, 6);
        // y2 = LN2(h)
        ln_to_bf16<<<M / 4, 256, 0, stream>>>(h, ln2w + l * DMODEL, ln2b + l * DMODEL, ybf);
        // g = gelu(y2 @ W1^T + b1) : N=3072, K=768 -> grid 24*98
        gemm_u<2><<<dim3(24 * 98), 256, 0, stream>>>(
            ybf, w1b + (size_t)l * 3072 * 768, b1 + (size_t)l * 3072, bigbf, 3072, 768, 24);
        // h += g @ W2^T + b2 : N=768, K=3072 -> grid 6*98
        gemm_u<1><<<dim3(6 * 98), 256, 0, stream>>>(
            bigbf, w2b + (size_t)l * 768 * 3072, b2 + (size_t)l * 768, h, 768, 3072, 6);
    }
}

// Round 5
// 1712.343 us; speedup vs baseline: 1.1061x; 1.1061x over previous
//
#include <hip/hip_runtime.h>

#define MTOT 25088
#define DMODEL 768
#define NH 12
#define WIN 49
#define NLAYER 2

typedef short bf16x8 __attribute__((ext_vector_type(8)));
typedef float f32x4 __attribute__((ext_vector_type(4)));
typedef unsigned short u16x4 __attribute__((ext_vector_type(4)));

__device__ __forceinline__ float bf2f(short s) {
    return __uint_as_float(((unsigned)(unsigned short)s) << 16);
}
__device__ __forceinline__ short f2b(float f) {
    unsigned x = __float_as_uint(f);
    unsigned r = x + 0x7FFFu + ((x >> 16) & 1u);
    return (short)(r >> 16);
}

// ---------------- fp32 -> bf16 weight conversion ----------------
__global__ __launch_bounds__(256) void cvt_f32_to_bf16(const float* __restrict__ in,
                                                       short* __restrict__ out, int n8) {
    int i = blockIdx.x * 256 + threadIdx.x;
    if (i >= n8) return;
    const float4* p = (const float4*)in + (size_t)i * 2;
    float4 a = p[0], b = p[1];
    bf16x8 o;
    o[0] = f2b(a.x); o[1] = f2b(a.y); o[2] = f2b(a.z); o[3] = f2b(a.w);
    o[4] = f2b(b.x); o[5] = f2b(b.y); o[6] = f2b(b.z); o[7] = f2b(b.w);
    *((bf16x8*)out + i) = o;
}

// ---------------- LayerNorm (fp32 in, bf16 out), 1 wave per row ----------------
__global__ __launch_bounds__(256) void ln_to_bf16(const float* __restrict__ h,
                                                  const float* __restrict__ w,
                                                  const float* __restrict__ b,
                                                  short* __restrict__ y) {
    int wave = threadIdx.x >> 6, lane = threadIdx.x & 63;
    int row = blockIdx.x * 4 + wave;
    const float4* hp = (const float4*)(h + (size_t)row * DMODEL);
    float4 v[3];
    float s = 0.f, s2 = 0.f;
#pragma unroll
    for (int c = 0; c < 3; c++) {
        v[c] = hp[lane + 64 * c];
        s += v[c].x + v[c].y + v[c].z + v[c].w;
        s2 += v[c].x * v[c].x + v[c].y * v[c].y + v[c].z * v[c].z + v[c].w * v[c].w;
    }
#pragma unroll
    for (int off = 32; off > 0; off >>= 1) {
        s += __shfl_xor(s, off);
        s2 += __shfl_xor(s2, off);
    }
    float mean = s * (1.f / DMODEL);
    float var = s2 * (1.f / DMODEL) - mean * mean;
    float rstd = rsqrtf(var + 1e-5f);
#pragma unroll
    for (int c = 0; c < 3; c++) {
        float4 wv = ((const float4*)w)[lane + 64 * c];
        float4 bv = ((const float4*)b)[lane + 64 * c];
        u16x4 o;
        o[0] = (unsigned short)f2b((v[c].x - mean) * rstd * wv.x + bv.x);
        o[1] = (unsigned short)f2b((v[c].y - mean) * rstd * wv.y + bv.y);
        o[2] = (unsigned short)f2b((v[c].z - mean) * rstd * wv.z + bv.z);
        o[3] = (unsigned short)f2b((v[c].w - mean) * rstd * wv.w + bv.w);
        *(u16x4*)(y + (size_t)row * DMODEL + (size_t)(lane + 64 * c) * 4) = o;
    }
}

// ---------------- GEMM: C[M,N] = A[M,K](bf16) @ B[N,K](bf16)^T + bias ----------------
// BM=128, BN=128, BK=32, 256 threads (4 waves 2x2), per-wave 64x64, 4 blocks/CU.
// EPI 0: bf16 = v+bias ; EPI 1: fp32 C += v+bias ; EPI 2: bf16 = gelu(v+bias)
#define BAR() asm volatile("s_barrier" ::: "memory")
#define LGKM0() do { asm volatile("s_waitcnt lgkmcnt(0)" ::: "memory"); __builtin_amdgcn_sched_barrier(0); } while (0)

template <int EPI>
__global__ __launch_bounds__(256, 4)
void gemm_v5(const short* __restrict__ A, const short* __restrict__ B,
             const float* __restrict__ bias, void* __restrict__ C,
             int N, int K, int gx) {
    // LDS: A [2][128][32]bf16 = 2*8KB at 0 ; B [2][128][32] = 2*8KB at 16384
    __shared__ char lds[32768];
    const int tid = threadIdx.x;
    const int wave = tid >> 6, lane = tid & 63;
    const int wr = wave >> 1, wc = wave & 1;
    const int fr = lane & 15, rq = lane >> 4;

    // bijective XCD swizzle (m204); consecutive lid share bm (A-band L2 reuse per XCD)
    int nwg = gridDim.x, orig = blockIdx.x;
    int q8 = nwg >> 3, r8 = nwg & 7;
    int xcd = orig & 7, lid = orig >> 3;
    int wg = (xcd < r8 ? xcd * (q8 + 1) : r8 * (q8 + 1) + (xcd - r8) * q8) + lid;
    const int bn = wg % gx, bm = wg / gx;
    const int row0 = bm * 128, col0 = bn * 128;
    const int nt = K >> 5;

    const short* Ag = A + (size_t)row0 * K;
    const short* Bg = B + (size_t)col0 * K;
    // staging: each gload covers 16 rows (seg); lane>>2 = row-in-seg, lane&3 = dest chunk.
    // LDS[row][chunk] holds global[row][chunk ^ ((row>>1)&3)]  (inverse pre-swizzle)
    const int lrow = lane >> 2;                                   // 0..15
    const int lcol = ((lane & 3) ^ ((lane >> 3) & 3)) * 8;        // elem offset in row

#define STAGE(T) do { int ts_ = ((T) < nt ? (T) : (nt - 1));                                       \
    _Pragma("unroll") for (int j = 0; j < 2; j++) {                                                \
      int seg_ = wave * 2 + j;                                                                     \
      __builtin_amdgcn_global_load_lds(                                                            \
        (const __attribute__((address_space(1))) void*)(Ag + (size_t)(seg_ * 16 + lrow) * K + ts_ * 32 + lcol), \
        (__attribute__((address_space(3))) void*)(lds + (((T) & 1) * 8192 + seg_ * 1024)),         \
        16, 0, 0); }                                                                               \
    _Pragma("unroll") for (int j = 0; j < 2; j++) {                                                \
      int seg_ = wave * 2 + j;                                                                     \
      __builtin_amdgcn_global_load_lds(                                                            \
        (const __attribute__((address_space(1))) void*)(Bg + (size_t)(seg_ * 16 + lrow) * K + ts_ * 32 + lcol), \
        (__attribute__((address_space(3))) void*)(lds + (16384 + ((T) & 1) * 8192 + seg_ * 1024)), \
        16, 0, 0); } } while (0)

    // read: row-major 64B rows; chunk index rq XOR'd with (row>>1)&3 -> 2-way (free)
#define LDA(m, BUF) (*(const bf16x8*)(lds + ((BUF) * 8192 +                                         \
    (wr * 64 + (m) * 16 + fr) * 64 + ((rq ^ ((fr >> 1) & 3)) << 4))))
#define LDB(n, BUF) (*(const bf16x8*)(lds + (16384 + (BUF) * 8192 +                                 \
    (wc * 64 + (n) * 16 + fr) * 64 + ((rq ^ ((fr >> 1) & 3)) << 4))))

    f32x4 acc[4][4] = {};

    STAGE(0);
    STAGE(1);
    asm volatile("s_waitcnt vmcnt(4)" ::: "memory");
    BAR();

    for (int t = 0; t < nt; t++) {
        const int buf = t & 1;
        bf16x8 a[4], b[4];
#pragma unroll
        for (int m = 0; m < 4; m++) a[m] = LDA(m, buf);
#pragma unroll
        for (int n = 0; n < 4; n++) b[n] = LDB(n, buf);
        LGKM0();            // own reads landed in regs
        BAR();              // all waves done reading buf
        STAGE(t + 2);       // overwrite buf with tile t+2
        __builtin_amdgcn_s_setprio(1);
#pragma unroll
        for (int m = 0; m < 4; m++) {
#pragma unroll
            for (int n = 0; n < 4; n++)
                acc[m][n] = __builtin_amdgcn_mfma_f32_16x16x32_bf16(a[m], b[n], acc[m][n], 0, 0, 0);
        }
        __builtin_amdgcn_s_setprio(0);
        asm volatile("s_waitcnt vmcnt(4)" ::: "memory");  // t+1 fully arrived
        BAR();
    }
    asm volatile("s_waitcnt vmcnt(0)" ::: "memory");  // drain before LDS dealloc

    // epilogue: C/D layout col=lane&15, row=(lane>>4)*4+reg
#pragma unroll
    for (int m = 0; m < 4; m++) {
#pragma unroll
        for (int n = 0; n < 4; n++) {
            int col = col0 + wc * 64 + n * 16 + fr;
            float bv = bias[col];
#pragma unroll
            for (int rg = 0; rg < 4; rg++) {
                int row = row0 + wr * 64 + m * 16 + rq * 4 + rg;
                size_t idx = (size_t)row * N + col;
                float v = acc[m][n][rg] + bv;
                if constexpr (EPI == 0) {
                    ((short*)C)[idx] = f2b(v);
                } else if constexpr (EPI == 1) {
                    float* O = (float*)C;
                    O[idx] = O[idx] + v;
                } else {
                    float g = 0.5f * v * (1.0f + erff(v * 0.70710678118654752f));
                    ((short*)C)[idx] = f2b(g);
                }
            }
        }
    }
#undef STAGE
#undef LDA
#undef LDB
}

// ---------------- windowed attention: 1 wave per (window, head) ----------------
__global__ __launch_bounds__(64) void attn_win(const short* __restrict__ qkv,
                                               short* __restrict__ out) {
    const int win = blockIdx.x / NH;
    const int head = blockIdx.x % NH;
    __shared__ __align__(16) short Ks[WIN * 64];
    __shared__ __align__(16) short Vs[WIN * 64];
    __shared__ float Ps[64 * WIN];
    const int lane = threadIdx.x;
    const size_t rb = (size_t)win * WIN;
    const int qoff = head * 64;

    for (int i = lane; i < WIN * 8; i += 64) {
        int r = i >> 3, c = (i & 7) * 8;
        const short* kg = qkv + (rb + r) * 2304 + DMODEL + qoff + c;
        *(bf16x8*)(Ks + r * 64 + c) = *(const bf16x8*)kg;
        *(bf16x8*)(Vs + r * 64 + c) = *(const bf16x8*)(kg + DMODEL);
    }
    __syncthreads();
    if (lane < WIN) {
        float q[64];
        const short* qg = qkv + (rb + lane) * 2304 + qoff;
#pragma unroll
        for (int c = 0; c < 8; c++) {
            bf16x8 t = *(const bf16x8*)(qg + c * 8);
#pragma unroll
            for (int d = 0; d < 8; d++) q[c * 8 + d] = bf2f(t[d]);
        }
        float m = -1e30f;
        for (int j = 0; j < WIN; j++) {
            float a = 0.f;
#pragma unroll
            for (int c = 0; c < 8; c++) {
                bf16x8 kv = *(const bf16x8*)(Ks + j * 64 + c * 8);
#pragma unroll
                for (int d = 0; d < 8; d++) a += q[c * 8 + d] * bf2f(kv[d]);
            }
            a *= 0.125f;
            Ps[lane * WIN + j] = a;
            m = fmaxf(m, a);
        }
        float sum = 0.f;
        for (int j = 0; j < WIN; j++) {
            float p = __expf(Ps[lane * WIN + j] - m);
            Ps[lane * WIN + j] = p;
            sum += p;
        }
        float rinv = 1.f / sum;
        short* og = out + (rb + lane) * DMODEL + qoff;
        for (int c = 0; c < 8; c++) {
            float o[8] = {0.f, 0.f, 0.f, 0.f, 0.f, 0.f, 0.f, 0.f};
            for (int j = 0; j < WIN; j++) {
                float p = Ps[lane * WIN + j];
                bf16x8 vv = *(const bf16x8*)(Vs + j * 64 + c * 8);
#pragma unroll
                for (int d = 0; d < 8; d++) o[d] += p * bf2f(vv[d]);
            }
            bf16x8 ov;
#pragma unroll
            for (int d = 0; d < 8; d++) ov[d] = f2b(o[d] * rinv);
            *(bf16x8*)(og + c * 8) = ov;
        }
    }
}

extern "C" void kernel_launch(void* const* d_in, const int* in_sizes, int n_in,
                              void* d_out, int out_size, void* d_ws, size_t ws_size,
                              hipStream_t stream) {
    const float* x    = (const float*)d_in[0];
    const float* Wqkv = (const float*)d_in[1];
    const float* bqkv = (const float*)d_in[2];
    const float* Wo   = (const float*)d_in[3];
    const float* bo   = (const float*)d_in[4];
    const float* ln1w = (const float*)d_in[5];
    const float* ln1b = (const float*)d_in[6];
    const float* W1   = (const float*)d_in[7];
    const float* b1   = (const float*)d_in[8];
    const float* W2   = (const float*)d_in[9];
    const float* b2   = (const float*)d_in[10];
    const float* ln2w = (const float*)d_in[11];
    const float* ln2b = (const float*)d_in[12];

    const int M = MTOT;
    char* ws = (char*)d_ws;
    short* ybf   = (short*)(ws);
    short* bigbf = (short*)(ws + 38535168);
    short* wqkvb = (short*)(ws + 38535168 + 154140672);
    short* wob   = wqkvb + (size_t)NLAYER * 2304 * 768;
    short* w1b   = wob + (size_t)NLAYER * 768 * 768;
    short* w2b   = w1b + (size_t)NLAYER * 3072 * 768;

    hipMemcpyAsync(d_out, (const void*)x, (size_t)M * DMODEL * sizeof(float),
                   hipMemcpyDeviceToDevice, stream);

    {
        size_t n;
        n = (size_t)NLAYER * 2304 * 768;
        cvt_f32_to_bf16<<<((int)(n / 8) + 255) / 256, 256, 0, stream>>>(Wqkv, wqkvb, (int)(n / 8));
        n = (size_t)NLAYER * 768 * 768;
        cvt_f32_to_bf16<<<((int)(n / 8) + 255) / 256, 256, 0, stream>>>(Wo, wob, (int)(n / 8));
        n = (size_t)NLAYER * 3072 * 768;
        cvt_f32_to_bf16<<<((int)(n / 8) + 255) / 256, 256, 0, stream>>>(W1, w1b, (int)(n / 8));
        n = (size_t)NLAYER * 768 * 3072;
        cvt_f32_to_bf16<<<((int)(n / 8) + 255) / 256, 256, 0, stream>>>(W2, w2b, (int)(n / 8));
    }

    float* h = (float*)d_out;
    for (int l = 0; l < NLAYER; l++) {
        // y = LN1(h)
        ln_to_bf16<<<M / 4, 256, 0, stream>>>(h, ln1w + l * DMODEL, ln1b + l * DMODEL, ybf);
        // qkv = y @ Wqkv^T + bqkv : N=2304, K=768 -> grid 18*196
        gemm_v5<0><<<dim3(18 * 196), 256, 0, stream>>>(
            ybf, wqkvb + (size_t)l * 2304 * 768, bqkv + (size_t)l * 2304, bigbf, 2304, 768, 18);
        // windowed attention (writes into ybf)
        attn_win<<<(M / WIN) * NH, 64, 0, stream>>>(bigbf, ybf);
        // h += attn @ Wo^T + bo : N=768, K=768 -> grid 6*196
        gemm_v5<1><<<dim3(6 * 196), 256, 0, stream>>>(
            ybf, wob + (size_t)l * 768 * 768, bo + (size_t)l * 768, h, 768, 768, 6);
        // y2 = LN2(h)
        ln_to_bf16<<<M / 4, 256, 0, stream>>>(h, ln2w + l * DMODEL, ln2b + l * DMODEL, ybf);
        // g = gelu(y2 @ W1^T + b1) : N=3072, K=768 -> grid 24*196
        gemm_v5<2><<<dim3(24 * 196), 256, 0, stream>>>(
            ybf, w1b + (size_t)l * 3072 * 768, b1 + (size_t)l * 3072, bigbf, 3072, 768, 24);
        // h += g @ W2^T + b2 : N=768, K=3072 -> grid 6*196
        gemm_v5<1><<<dim3(6 * 196), 256, 0, stream>>>(
            bigbf, w2b + (size_t)l * 768 * 3072, b2 + (size_t)l * 768, h, 768, 3072, 6);
    }
}